// Round 9
// baseline (355.035 us; speedup 1.0000x reference)
//
#include <hip/hip_runtime.h>

// Problem: B=4, S=2048, D=1024, H=16, HD=64.
#define NB 4
#define NS 2048
#define ND 1024
#define NH 16
#define NE 64
#define NM (NB*NS)   // 8192 rows

typedef __attribute__((ext_vector_type(8))) __bf16 bf16x8;           // MFMA A/B frag (4 VGPRs)
typedef __attribute__((ext_vector_type(4))) float f32x4;             // MFMA C/D frag

__device__ __forceinline__ float bf2f(unsigned short h) {
  union { unsigned u; float f; } c; c.u = ((unsigned)h) << 16; return c.f;
}
__device__ __forceinline__ unsigned short f2bf(float f) {
  union { float f; unsigned u; } c; c.f = f;
  return (unsigned short)((c.u + 0x7fffu + ((c.u >> 16) & 1u)) >> 16);
}
__device__ __forceinline__ void load16_to_lds(const void* g, void* l) {
  __builtin_amdgcn_global_load_lds(
      (__attribute__((address_space(1))) void*)(void*)(unsigned long long)(const char*)g,
      (__attribute__((address_space(3))) void*)l, 16, 0, 0);
}

// ---------- dtype detection: is d_in data bf16 (1) or fp32 (0)? ----------
__global__ void detect_dtype(const unsigned* __restrict__ x, int* __restrict__ flag) {
  __shared__ int cnt;
  if (threadIdx.x == 0) cnt = 0;
  __syncthreads();
  unsigned w = x[((unsigned)threadIdx.x * 16381u) & ((1u << 21) - 1u)];
  unsigned lo = w & 0xFFFFu;
  int e = (int)((lo >> 7) & 0xFF);
  int plausible = (lo == 0u) || (e >= 100 && e <= 142);
  atomicAdd(&cnt, plausible);
  __syncthreads();
  if (threadIdx.x == 0) *flag = (cnt >= 192) ? 1 : 0;
}

// ---------- canonicalize any input to bf16 ----------
__global__ void conv_to_bf16(const void* __restrict__ src, unsigned short* __restrict__ dst,
                             int n, const int* __restrict__ flag) {
  int stride = gridDim.x * blockDim.x;
  int i0 = blockIdx.x * blockDim.x + threadIdx.x;
  if (*flag) {
    const unsigned short* s = (const unsigned short*)src;
    for (int i = i0; i < n; i += stride) dst[i] = s[i];
  } else {
    const float* s = (const float*)src;
    for (int i = i0; i < n; i += stride) dst[i] = f2bf(s[i]);
  }
}

// ---------- fused convert+transpose: in[K][N] (bf16 or fp32 per flag) -> out[N][K] bf16 ----------
__global__ __launch_bounds__(256) void transpose_conv(const void* __restrict__ in,
                                                      unsigned short* __restrict__ out,
                                                      int K, int N, const int* __restrict__ flag) {
  __shared__ unsigned short tile[32][33];
  int n0 = blockIdx.x * 32, k0 = blockIdx.y * 32;
  int tx = threadIdx.x, ty = threadIdx.y;   // (32,8)
  if (*flag) {
    const unsigned short* p = (const unsigned short*)in;
#pragma unroll
    for (int i = 0; i < 4; ++i)
      tile[ty + 8*i][tx] = p[(size_t)(k0 + ty + 8*i) * N + n0 + tx];
  } else {
    const float* p = (const float*)in;
#pragma unroll
    for (int i = 0; i < 4; ++i)
      tile[ty + 8*i][tx] = f2bf(p[(size_t)(k0 + ty + 8*i) * N + n0 + tx]);
  }
  __syncthreads();
#pragma unroll
  for (int i = 0; i < 4; ++i)
    out[(size_t)(n0 + ty + 8*i) * K + k0 + tx] = tile[tx][ty + 8*i];
}

// ---------- v5 GEMM core: T3 minimum 2-phase recipe (guide-verified 622-682 TF class) ----
#define BUFB 49152            // bytes per buf: A 256*128 + B 128*128

__device__ __forceinline__ void gemm_core_v5(const unsigned short* __restrict__ Ag,
                                             const unsigned short* __restrict__ Btg,
                                             int m0, int n0,
                                             unsigned short* sm,
                                             f32x4 (&acc)[4][4]) {
  char* smb = (char*)sm;
  const int t = threadIdx.x;                 // 0..511
  const int lane = t & 63, w = t >> 6;       // 8 waves
  const int wr = w >> 1, wc = w & 1;         // 4M x 2N, wave tile 64x64
  const int frm = lane & 15, qd = lane >> 4;
  const int px0 = ((qd    ) ^ (frm & 7)) * 16;   // ks=0 swizzled chunk byte offset
  const int px1 = ((4 + qd) ^ (frm & 7)) * 16;   // ks=1
  const int NT = ND / 64;                    // 16 K-tiles

  auto stage = [&](int kt, int b) {
    char* Ab = smb + b * BUFB;
    char* Bb = Ab + 32768;
    int kk = kt * 64;
#pragma unroll
    for (int u = 0; u < 4; ++u) {            // A: 256x64 = 2048 chunks of 16B
      int ci = u * 512 + t;
      int row = ci >> 3, c = ci & 7, l = c ^ (row & 7);
      load16_to_lds(Ag + (size_t)(m0 + row) * ND + kk + l * 8, Ab + ci * 16);
    }
#pragma unroll
    for (int u = 0; u < 2; ++u) {            // B: 128x64 = 1024 chunks of 16B
      int ci = u * 512 + t;
      int row = ci >> 3, c = ci & 7, l = c ^ (row & 7);
      load16_to_lds(Btg + (size_t)(n0 + row) * ND + kk + l * 8, Bb + ci * 16);
    }
  };

  // prologue: stage tile 0 into buf 0, drain, barrier
  stage(0, 0);
  asm volatile("s_waitcnt vmcnt(0)\n\ts_barrier" ::: "memory");

  for (int kt = 0; kt < NT; ++kt) {
    const int cur = kt & 1;
    const char* Ab = smb + cur * BUFB;
    const char* Bb = Ab + 32768;

    if (kt + 1 < NT) stage(kt + 1, cur ^ 1);   // issue prefetch FIRST (stays in flight)

    bf16x8 a[4][2], b[4][2];
#pragma unroll
    for (int i = 0; i < 4; ++i) {
      int row = 64*wr + 16*i + frm;
      a[i][0] = *(const bf16x8*)(Ab + row * 128 + px0);
      a[i][1] = *(const bf16x8*)(Ab + row * 128 + px1);
    }
#pragma unroll
    for (int j = 0; j < 4; ++j) {
      int row = 64*wc + 16*j + frm;
      b[j][0] = *(const bf16x8*)(Bb + row * 128 + px0);
      b[j][1] = *(const bf16x8*)(Bb + row * 128 + px1);
    }
    asm volatile("s_waitcnt lgkmcnt(0)" ::: "memory");
    __builtin_amdgcn_s_setprio(1);
#pragma unroll
    for (int i = 0; i < 4; ++i)
#pragma unroll
      for (int j = 0; j < 4; ++j) {
        acc[i][j] = __builtin_amdgcn_mfma_f32_16x16x32_bf16(a[i][0], b[j][0], acc[i][j], 0, 0, 0);
        acc[i][j] = __builtin_amdgcn_mfma_f32_16x16x32_bf16(a[i][1], b[j][1], acc[i][j], 0, 0, 0);
      }
    __builtin_amdgcn_s_setprio(0);
    if (kt + 1 < NT)
      asm volatile("s_waitcnt vmcnt(0)\n\ts_barrier" ::: "memory");   // next tile ready
    // kt == NT-1: fall through to epilogue (register-only)
  }
}

// ---------- QKV projection, v5 core; scatter q/k:(B,H,S,E), v:(B,H,E,S) ----------
__global__ __launch_bounds__(512, 2) void gemm_qkv_v5(const unsigned short* __restrict__ X,
                                                      const unsigned short* __restrict__ W1T,
                                                      const unsigned short* __restrict__ battn,
                                                      unsigned short* __restrict__ qb,
                                                      unsigned short* __restrict__ kb,
                                                      unsigned short* __restrict__ vb) {
  __shared__ unsigned short sm[2 * 384 * 64];        // 96 KiB
  // XCD bijective swizzle: 768 = 8*96; XCD k owns 4 consecutive m-panels x all 24 n-panels.
  int flat = blockIdx.x + 24 * blockIdx.y;
  int virt = (flat & 7) * 96 + (flat >> 3);
  const int n0 = (virt % 24) * 128;
  const int m0 = (virt / 24) * 256;

  f32x4 acc[4][4] = {};
  gemm_core_v5(X, W1T, m0, n0, sm, acc);

  const int t = threadIdx.x, lane = t & 63, w = t >> 6;
  const int wr = w >> 1, wc = w & 1;
  const int coln = lane & 15, rbase = (lane >> 4) * 4;
#pragma unroll
  for (int j = 0; j < 4; ++j) {
    int nn = n0 + 64*wc + 16*j + coln;       // 0..3071
    int qq = nn >> 10;                       // 0=q 1=k 2=v
    int h  = (nn >> 6) & 15;
    int e  = nn & 63;
    float bias = bf2f(battn[nn]);
    float scale = (qq == 0) ? (0.125f * 1.44269504f) : 1.0f;
    if (qq == 2) {
      // V (B,H,E,S): 4 rr values are 4 consecutive s -> one 8B packed store
#pragma unroll
      for (int i = 0; i < 4; ++i) {
        int mm0 = m0 + 64*wr + 16*i + rbase;
        int bb = mm0 >> 11, s0 = mm0 & 2047;
        unsigned long long pk = 0;
#pragma unroll
        for (int rr = 0; rr < 4; ++rr) {
          float v = acc[i][j][rr] + bias;
          pk |= ((unsigned long long)f2bf(v)) << (16 * rr);
        }
        size_t idx = (((size_t)bb * NH + h) * NE + e) * NS + s0;
        *(unsigned long long*)(vb + idx) = pk;
      }
    } else {
      unsigned short* dst = (qq == 0) ? qb : kb;
#pragma unroll
      for (int i = 0; i < 4; ++i) {
#pragma unroll
        for (int rr = 0; rr < 4; ++rr) {
          int mm = m0 + 64*wr + 16*i + rbase + rr;
          int bb = mm >> 11, s = mm & 2047;
          float v = (acc[i][j][rr] + bias) * scale;
          dst[(((size_t)bb * NH + h) * NS + s) * NE + e] = f2bf(v);
        }
      }
    }
  }
}

// ---------- output projection, v5 core; store dtype per flag ----------
__global__ __launch_bounds__(512, 2) void gemm_proj_v5(const unsigned short* __restrict__ A,
                                                       const unsigned short* __restrict__ W2T,
                                                       const unsigned short* __restrict__ bproj,
                                                       void* __restrict__ outv,
                                                       const int* __restrict__ flag) {
  __shared__ unsigned short sm[2 * 384 * 64];        // 96 KiB
  // 256 blocks = exactly 1/CU; XCD swizzle: 256 = 8*32.
  int flat = blockIdx.x + 8 * blockIdx.y;
  int virt = (flat & 7) * 32 + (flat >> 3);
  const int n0 = (virt % 8) * 128;
  const int m0 = (virt / 8) * 256;

  f32x4 acc[4][4] = {};
  gemm_core_v5(A, W2T, m0, n0, sm, acc);

  const int isbf = *flag;
  unsigned short* out16 = (unsigned short*)outv;
  float* out32 = (float*)outv;
  const int t = threadIdx.x, lane = t & 63, w = t >> 6;
  const int wr = w >> 1, wc = w & 1;
  const int coln = lane & 15, rbase = (lane >> 4) * 4;
#pragma unroll
  for (int j = 0; j < 4; ++j) {
    int nn = n0 + 64*wc + 16*j + coln;
    float bias = bf2f(bproj[nn]);
#pragma unroll
    for (int i = 0; i < 4; ++i) {
#pragma unroll
      for (int rr = 0; rr < 4; ++rr) {
        int mm = m0 + 64*wr + 16*i + rbase + rr;
        float v = acc[i][j][rr] + bias;
        if (isbf) out16[(size_t)mm * ND + nn] = f2bf(v);
        else      out32[(size_t)mm * ND + nn] = v;
      }
    }
  }
}

// ---------- causal flash attention: R9 fat blocks (QBLK=256, KVBLK=64, 8 waves) ----------
// R8 post-mortem: no pipe saturated (LDS~55%, VALU~51%, MFMA~19%) -> cross-pipe serial
// chain, 136 x 32-key traversals/CU. R9 cuts traversals ~4x: QBLK=256 (8 waves, wave
// owns 32 rows), KVBLK=64. Grid 512 = 64bh x 8 chunks at 2 blocks/CU; chunk pairing
// {0,7}{1,6}{2,5}{3,4} -> co-resident pair sums 36 tiles ALWAYS (uniform makespan);
// pair shares bh -> K/V L2 locality. LDS 64K: QP 32K (Q 256x64 then P 256 rows x 64
// keys, octet-swizzled) + K dbuf 2x8K + V dbuf 2x8K (per slot: two 32-key Vt subtiles).
// Fragment algebra: store octet lo=2c+(li>>3) (c=0..3) covers all 8 octets; A-operand
// reads at sw0 (k=8qd+j) and sw1 (k=32+8qd+j) -- same involution as Q/K (derived, not
// guessed). Staging: 1 K-call + 1 V-call per tile (512 thr x 16B = 8KB) -> verified
// vmcnt(2) dbuf discipline carries over verbatim.
__global__ __launch_bounds__(512, 4) void attn_causal(const unsigned short* __restrict__ qb,
                                                      const unsigned short* __restrict__ kb,
                                                      const unsigned short* __restrict__ vtb,
                                                      unsigned short* __restrict__ ob) {
  __shared__ unsigned short QPs[256 * 64];           // 32K: Q then P
  __shared__ unsigned short Ks[2][64 * 64];          // 16K
  __shared__ unsigned short Vt[2][2 * 32 * 64];      // 16K (2 subtiles per slot)

  int t = threadIdx.x, lane = t & 63, w = t >> 6;    // 8 waves
  int qd = lane >> 4, li = lane & 15;
  int sw0 = ((qd ^ (li & 7)) * 8);
  int sw1 = (((4 + qd) ^ (li & 7)) * 8);

  const int tab[4][2] = {{0,7},{1,6},{2,5},{3,4}};
  int bi = blockIdx.x;
  int bh = bi & 63;
  int qc = tab[(bi >> 6) & 3][bi >> 8];
  int q0 = qc * 256;
  int NT = 4 * qc + 4;                       // 64-key tiles
  size_t base = (size_t)bh * NS * NE;
  int bb = bh >> 4, hh = bh & 15;

  bf16x8 onesf;
#pragma unroll
  for (int j = 0; j < 8; ++j) onesf[j] = (__bf16)1.0f;

  // K staging (one call per 64-key tile: 512 thr x 16B = 8KB)
  int r8 = t >> 3;                           // 0..63 = key row
  int lswk = (t & 7) ^ (r8 & 7);
  const char* ksrc = (const char*)(kb + base + (size_t)r8 * NE + lswk * 8);
  char* kdst = (char*)Ks[0] + t * 16;        // slot stride 8192 B
  // V staging (one call per tile; sub = key-half)
  int sub = t >> 8, tt = t & 255;
  int rv = tt >> 3;
  int lswv = (tt & 7) ^ (rv & 7);
  int ev = 2 * rv + (lswv >> 2);
  const char* vsrc = (const char*)(vtb + base + (size_t)ev * NS + sub * 32 + (lswv & 3) * 8);
  char* vdst = (char*)Vt[0] + sub * 4096 + tt * 16;

  auto stage_kv = [&](int buf) {             // stages the NEXT sequential 64-key tile
    load16_to_lds(ksrc, kdst + buf * 8192);
    load16_to_lds(vsrc, vdst + buf * 8192);
    ksrc += (size_t)64 * NE * 2;             // +8192 B (64 keys)
    vsrc += 64 * 2;                          // +128 B
  };

  // prologue: stage Q (256x64, 4 calls) + K/V tile 0
#pragma unroll
  for (int c = 0; c < 4; ++c) {
    int ch = c * 512 + t;
    int r = ch >> 3, jl = (ch & 7) ^ (r & 7);
    load16_to_lds(qb + base + (size_t)(q0 + r) * NE + jl * 8, (char*)QPs + ch * 16);
  }
  stage_kv(0);
  asm volatile("s_waitcnt vmcnt(2)\n\ts_barrier" ::: "memory");  // Q landed, kv0 in flight

  bf16x8 qa[2][2];
#pragma unroll
  for (int i = 0; i < 2; ++i) {
    const unsigned short* qr = QPs + (32*w + 16*i + li) * 64;
    qa[i][0] = *(const bf16x8*)(qr + sw0);
    qa[i][1] = *(const bf16x8*)(qr + sw1);
  }

  f32x4 o[2][4] = {};
  f32x4 lacc[2] = {};

  for (int kt = 0; kt < NT; ++kt) {
    int cur = kt & 1;
    // all waves done reading buf[cur^1] (and, at kt=0, Q) -> safe to restage it
    asm volatile("s_waitcnt lgkmcnt(0)\n\ts_barrier" ::: "memory");
    if (kt + 1 < NT) {
      stage_kv(cur ^ 1);
      asm volatile("s_waitcnt vmcnt(2)\n\ts_barrier" ::: "memory");  // tile kt landed
    } else {
      asm volatile("s_waitcnt vmcnt(0)\n\ts_barrier" ::: "memory");
    }

    int k0 = kt * 64;
    const unsigned short* Ksc = Ks[cur];
    const unsigned short* Vtc = Vt[cur];

    bf16x8 kfr[4][2];
#pragma unroll
    for (int c = 0; c < 4; ++c) {
      const unsigned short* kr = Ksc + (16*c + li) * 64;
      kfr[c][0] = *(const bf16x8*)(kr + sw0);
      kfr[c][1] = *(const bf16x8*)(kr + sw1);
    }

    int need_mask = (k0 + 63 > q0 + 32*w);   // wave's min row = q0+32w
    __builtin_amdgcn_s_setprio(1);
#pragma unroll
    for (int i = 0; i < 2; ++i) {
#pragma unroll
      for (int c = 0; c < 4; ++c) {
        f32x4 s = {};
        s = __builtin_amdgcn_mfma_f32_16x16x32_bf16(qa[i][0], kfr[c][0], s, 0, 0, 0);
        s = __builtin_amdgcn_mfma_f32_16x16x32_bf16(qa[i][1], kfr[c][1], s, 0, 0, 0);
#pragma unroll
        for (int rr = 0; rr < 4; ++rr) {
          float pv = exp2f(s[rr]);
          if (need_mask) {
            int colk = k0 + 16*c + li;
            int rowq = q0 + 32*w + 16*i + qd*4 + rr;
            if (colk > rowq) pv = 0.f;
          }
          int prow = 32*w + 16*i + qd*4 + rr;
          int lo = 2*c + (li >> 3);
          *(unsigned short*)((char*)QPs +
              (prow * 64 + ((lo ^ (prow & 7)) * 8) + (li & 7)) * 2) =
              (unsigned short)(__float_as_uint(pv) >> 16);
        }
      }
    }
    __builtin_amdgcn_s_setprio(0);

    // read P as A-operand (wave-local rows; in-order LDS => no barrier)
    bf16x8 pa[2][2];
#pragma unroll
    for (int i = 0; i < 2; ++i) {
      const unsigned short* pr = QPs + (32*w + 16*i + li) * 64;
      pa[i][0] = *(const bf16x8*)(pr + sw0);   // keys 0..31  (k=8qd+j)
      pa[i][1] = *(const bf16x8*)(pr + sw1);   // keys 32..63
    }

    __builtin_amdgcn_s_setprio(1);
#pragma unroll
    for (int i = 0; i < 2; ++i) {
      lacc[i] = __builtin_amdgcn_mfma_f32_16x16x32_bf16(pa[i][0], onesf, lacc[i], 0, 0, 0);
      lacc[i] = __builtin_amdgcn_mfma_f32_16x16x32_bf16(pa[i][1], onesf, lacc[i], 0, 0, 0);
    }

    // O += P V : vf0 from subtile0 (keys 0..31), vf1 from subtile1 (keys 32..63)
#pragma unroll
    for (int c2 = 0; c2 < 4; ++c2) {
      const unsigned short* vr0 = Vtc + (8*c2 + (li >> 1)) * 64;
      const unsigned short* vr1 = vr0 + 2048;              // +4096 B
      int vo = ((((li & 1) * 4 + qd) ^ ((li >> 1) & 7)) * 8);
      bf16x8 vf0 = *(const bf16x8*)(vr0 + vo);
      bf16x8 vf1 = *(const bf16x8*)(vr1 + vo);
#pragma unroll
      for (int i = 0; i < 2; ++i) {
        o[i][c2] = __builtin_amdgcn_mfma_f32_16x16x32_bf16(pa[i][0], vf0, o[i][c2], 0, 0, 0);
        o[i][c2] = __builtin_amdgcn_mfma_f32_16x16x32_bf16(pa[i][1], vf1, o[i][c2], 0, 0, 0);
      }
    }
    __builtin_amdgcn_s_setprio(0);
  }

  // write O to (B,S,H,E)
#pragma unroll
  for (int i = 0; i < 2; ++i)
#pragma unroll
    for (int c = 0; c < 4; ++c)
#pragma unroll
      for (int rr = 0; rr < 4; ++rr) {
        int rowm = 32*w + 16*i + qd*4 + rr;
        float inv = 1.0f / fmaxf(lacc[i][rr], 1e-30f);
        float ov = o[i][c][rr] * inv;
        int e = 16*c + li;
        ob[(((size_t)bb * NS + (q0 + rowm)) * NH + hh) * NE + e] = f2bf(ov);
      }
}

extern "C" void kernel_launch(void* const* d_in, const int* in_sizes, int n_in,
                              void* d_out, int out_size, void* d_ws, size_t ws_size,
                              hipStream_t stream) {
  (void)in_sizes; (void)n_in; (void)out_size; (void)ws_size;
  char* ws = (char*)d_ws;
  unsigned short* W1T = (unsigned short*)(ws);                       // 6,291,456
  unsigned short* W2T = (unsigned short*)(ws + 6291456);             // 2,097,152
  unsigned short* qb  = (unsigned short*)(ws + 8388608);             // 16 MB
  unsigned short* kb  = (unsigned short*)(ws + 25165824);            // 16 MB
  unsigned short* vb  = (unsigned short*)(ws + 41943040);            // 16 MB (B,H,E,S)
  unsigned short* ob  = (unsigned short*)(ws + 58720256);            // 16 MB
  unsigned short* bac = (unsigned short*)(ws + 75497472);            // 8 KB
  unsigned short* bpc = (unsigned short*)(ws + 75505664);            // 8 KB
  int*            flg = (int*)(ws + 75513856);
  unsigned short* xc  = ob;   // converted x, dead before ob written

  detect_dtype<<<1, 256, 0, stream>>>((const unsigned*)d_in[0], flg);
  conv_to_bf16<<<2048, 256, 0, stream>>>(d_in[0], xc,  NB*NS*ND, flg);
  conv_to_bf16<<<12,   256, 0, stream>>>(d_in[2], bac, 3*NH*NE, flg);
  conv_to_bf16<<<4,    256, 0, stream>>>(d_in[4], bpc, ND, flg);

  transpose_conv<<<dim3(3072/32, 1024/32), dim3(32, 8), 0, stream>>>(d_in[1], W1T, 1024, 3072, flg);
  transpose_conv<<<dim3(1024/32, 1024/32), dim3(32, 8), 0, stream>>>(d_in[3], W2T, 1024, 1024, flg);
  gemm_qkv_v5<<<dim3(3072/128, NM/256), 512, 0, stream>>>(xc, W1T, bac, qb, kb, vb);
  attn_causal<<<dim3(512), 512, 0, stream>>>(qb, kb, vb, ob);
  gemm_proj_v5<<<dim3(1024/128, NM/256), 512, 0, stream>>>(ob, W2T, bpc, d_out, flg);
}

// Round 10
// 324.394 us; speedup vs baseline: 1.0945x; 1.0945x over previous
//
#include <hip/hip_runtime.h>

// Problem: B=4, S=2048, D=1024, H=16, HD=64.
#define NB 4
#define NS 2048
#define ND 1024
#define NH 16
#define NE 64
#define NM (NB*NS)   // 8192 rows

typedef __attribute__((ext_vector_type(8))) __bf16 bf16x8;           // MFMA A/B frag (4 VGPRs)
typedef __attribute__((ext_vector_type(4))) float f32x4;             // MFMA C/D frag

__device__ __forceinline__ float bf2f(unsigned short h) {
  union { unsigned u; float f; } c; c.u = ((unsigned)h) << 16; return c.f;
}
__device__ __forceinline__ unsigned short f2bf(float f) {
  union { float f; unsigned u; } c; c.f = f;
  return (unsigned short)((c.u + 0x7fffu + ((c.u >> 16) & 1u)) >> 16);
}
__device__ __forceinline__ void load16_to_lds(const void* g, void* l) {
  __builtin_amdgcn_global_load_lds(
      (__attribute__((address_space(1))) void*)(void*)(unsigned long long)(const char*)g,
      (__attribute__((address_space(3))) void*)l, 16, 0, 0);
}

// ---------- dtype detection: is d_in data bf16 (1) or fp32 (0)? ----------
__global__ void detect_dtype(const unsigned* __restrict__ x, int* __restrict__ flag) {
  __shared__ int cnt;
  if (threadIdx.x == 0) cnt = 0;
  __syncthreads();
  unsigned w = x[((unsigned)threadIdx.x * 16381u) & ((1u << 21) - 1u)];
  unsigned lo = w & 0xFFFFu;
  int e = (int)((lo >> 7) & 0xFF);
  int plausible = (lo == 0u) || (e >= 100 && e <= 142);
  atomicAdd(&cnt, plausible);
  __syncthreads();
  if (threadIdx.x == 0) *flag = (cnt >= 192) ? 1 : 0;
}

// ---------- canonicalize any input to bf16 ----------
__global__ void conv_to_bf16(const void* __restrict__ src, unsigned short* __restrict__ dst,
                             int n, const int* __restrict__ flag) {
  int stride = gridDim.x * blockDim.x;
  int i0 = blockIdx.x * blockDim.x + threadIdx.x;
  if (*flag) {
    const unsigned short* s = (const unsigned short*)src;
    for (int i = i0; i < n; i += stride) dst[i] = s[i];
  } else {
    const float* s = (const float*)src;
    for (int i = i0; i < n; i += stride) dst[i] = f2bf(s[i]);
  }
}

// ---------- fused convert+transpose: in[K][N] (bf16 or fp32 per flag) -> out[N][K] bf16 ----------
__global__ __launch_bounds__(256) void transpose_conv(const void* __restrict__ in,
                                                      unsigned short* __restrict__ out,
                                                      int K, int N, const int* __restrict__ flag) {
  __shared__ unsigned short tile[32][33];
  int n0 = blockIdx.x * 32, k0 = blockIdx.y * 32;
  int tx = threadIdx.x, ty = threadIdx.y;   // (32,8)
  if (*flag) {
    const unsigned short* p = (const unsigned short*)in;
#pragma unroll
    for (int i = 0; i < 4; ++i)
      tile[ty + 8*i][tx] = p[(size_t)(k0 + ty + 8*i) * N + n0 + tx];
  } else {
    const float* p = (const float*)in;
#pragma unroll
    for (int i = 0; i < 4; ++i)
      tile[ty + 8*i][tx] = f2bf(p[(size_t)(k0 + ty + 8*i) * N + n0 + tx]);
  }
  __syncthreads();
#pragma unroll
  for (int i = 0; i < 4; ++i)
    out[(size_t)(n0 + ty + 8*i) * K + k0 + tx] = tile[tx][ty + 8*i];
}

// ---------- v5 GEMM core: T3 minimum 2-phase recipe (guide-verified 622-682 TF class) ----
#define BUFB 49152            // bytes per buf: A 256*128 + B 128*128

__device__ __forceinline__ void gemm_core_v5(const unsigned short* __restrict__ Ag,
                                             const unsigned short* __restrict__ Btg,
                                             int m0, int n0,
                                             unsigned short* sm,
                                             f32x4 (&acc)[4][4]) {
  char* smb = (char*)sm;
  const int t = threadIdx.x;                 // 0..511
  const int lane = t & 63, w = t >> 6;       // 8 waves
  const int wr = w >> 1, wc = w & 1;         // 4M x 2N, wave tile 64x64
  const int frm = lane & 15, qd = lane >> 4;
  const int px0 = ((qd    ) ^ (frm & 7)) * 16;   // ks=0 swizzled chunk byte offset
  const int px1 = ((4 + qd) ^ (frm & 7)) * 16;   // ks=1
  const int NT = ND / 64;                    // 16 K-tiles

  auto stage = [&](int kt, int b) {
    char* Ab = smb + b * BUFB;
    char* Bb = Ab + 32768;
    int kk = kt * 64;
#pragma unroll
    for (int u = 0; u < 4; ++u) {            // A: 256x64 = 2048 chunks of 16B
      int ci = u * 512 + t;
      int row = ci >> 3, c = ci & 7, l = c ^ (row & 7);
      load16_to_lds(Ag + (size_t)(m0 + row) * ND + kk + l * 8, Ab + ci * 16);
    }
#pragma unroll
    for (int u = 0; u < 2; ++u) {            // B: 128x64 = 1024 chunks of 16B
      int ci = u * 512 + t;
      int row = ci >> 3, c = ci & 7, l = c ^ (row & 7);
      load16_to_lds(Btg + (size_t)(n0 + row) * ND + kk + l * 8, Bb + ci * 16);
    }
  };

  // prologue: stage tile 0 into buf 0, drain, barrier
  stage(0, 0);
  asm volatile("s_waitcnt vmcnt(0)\n\ts_barrier" ::: "memory");

  for (int kt = 0; kt < NT; ++kt) {
    const int cur = kt & 1;
    const char* Ab = smb + cur * BUFB;
    const char* Bb = Ab + 32768;

    if (kt + 1 < NT) stage(kt + 1, cur ^ 1);   // issue prefetch FIRST (stays in flight)

    bf16x8 a[4][2], b[4][2];
#pragma unroll
    for (int i = 0; i < 4; ++i) {
      int row = 64*wr + 16*i + frm;
      a[i][0] = *(const bf16x8*)(Ab + row * 128 + px0);
      a[i][1] = *(const bf16x8*)(Ab + row * 128 + px1);
    }
#pragma unroll
    for (int j = 0; j < 4; ++j) {
      int row = 64*wc + 16*j + frm;
      b[j][0] = *(const bf16x8*)(Bb + row * 128 + px0);
      b[j][1] = *(const bf16x8*)(Bb + row * 128 + px1);
    }
    asm volatile("s_waitcnt lgkmcnt(0)" ::: "memory");
    __builtin_amdgcn_s_setprio(1);
#pragma unroll
    for (int i = 0; i < 4; ++i)
#pragma unroll
      for (int j = 0; j < 4; ++j) {
        acc[i][j] = __builtin_amdgcn_mfma_f32_16x16x32_bf16(a[i][0], b[j][0], acc[i][j], 0, 0, 0);
        acc[i][j] = __builtin_amdgcn_mfma_f32_16x16x32_bf16(a[i][1], b[j][1], acc[i][j], 0, 0, 0);
      }
    __builtin_amdgcn_s_setprio(0);
    if (kt + 1 < NT)
      asm volatile("s_waitcnt vmcnt(0)\n\ts_barrier" ::: "memory");   // next tile ready
    // kt == NT-1: fall through to epilogue (register-only)
  }
}

// ---------- QKV projection, v5 core; scatter q/k:(B,H,S,E), v:(B,H,E,S) ----------
__global__ __launch_bounds__(512, 2) void gemm_qkv_v5(const unsigned short* __restrict__ X,
                                                      const unsigned short* __restrict__ W1T,
                                                      const unsigned short* __restrict__ battn,
                                                      unsigned short* __restrict__ qb,
                                                      unsigned short* __restrict__ kb,
                                                      unsigned short* __restrict__ vb) {
  __shared__ unsigned short sm[2 * 384 * 64];        // 96 KiB
  // XCD bijective swizzle: 768 = 8*96; XCD k owns 4 consecutive m-panels x all 24 n-panels.
  int flat = blockIdx.x + 24 * blockIdx.y;
  int virt = (flat & 7) * 96 + (flat >> 3);
  const int n0 = (virt % 24) * 128;
  const int m0 = (virt / 24) * 256;

  f32x4 acc[4][4] = {};
  gemm_core_v5(X, W1T, m0, n0, sm, acc);

  const int t = threadIdx.x, lane = t & 63, w = t >> 6;
  const int wr = w >> 1, wc = w & 1;
  const int coln = lane & 15, rbase = (lane >> 4) * 4;
#pragma unroll
  for (int j = 0; j < 4; ++j) {
    int nn = n0 + 64*wc + 16*j + coln;       // 0..3071
    int qq = nn >> 10;                       // 0=q 1=k 2=v
    int h  = (nn >> 6) & 15;
    int e  = nn & 63;
    float bias = bf2f(battn[nn]);
    float scale = (qq == 0) ? (0.125f * 1.44269504f) : 1.0f;
    if (qq == 2) {
      // V (B,H,E,S): 4 rr values are 4 consecutive s -> one 8B packed store
#pragma unroll
      for (int i = 0; i < 4; ++i) {
        int mm0 = m0 + 64*wr + 16*i + rbase;
        int bb = mm0 >> 11, s0 = mm0 & 2047;
        unsigned long long pk = 0;
#pragma unroll
        for (int rr = 0; rr < 4; ++rr) {
          float v = acc[i][j][rr] + bias;
          pk |= ((unsigned long long)f2bf(v)) << (16 * rr);
        }
        size_t idx = (((size_t)bb * NH + h) * NE + e) * NS + s0;
        *(unsigned long long*)(vb + idx) = pk;
      }
    } else {
      unsigned short* dst = (qq == 0) ? qb : kb;
#pragma unroll
      for (int i = 0; i < 4; ++i) {
#pragma unroll
        for (int rr = 0; rr < 4; ++rr) {
          int mm = m0 + 64*wr + 16*i + rbase + rr;
          int bb = mm >> 11, s = mm & 2047;
          float v = (acc[i][j][rr] + bias) * scale;
          dst[(((size_t)bb * NH + h) * NS + s) * NE + e] = f2bf(v);
        }
      }
    }
  }
}

// ---------- output projection, v5 core; store dtype per flag ----------
__global__ __launch_bounds__(512, 2) void gemm_proj_v5(const unsigned short* __restrict__ A,
                                                       const unsigned short* __restrict__ W2T,
                                                       const unsigned short* __restrict__ bproj,
                                                       void* __restrict__ outv,
                                                       const int* __restrict__ flag) {
  __shared__ unsigned short sm[2 * 384 * 64];        // 96 KiB
  // 256 blocks = exactly 1/CU; XCD swizzle: 256 = 8*32.
  int flat = blockIdx.x + 8 * blockIdx.y;
  int virt = (flat & 7) * 32 + (flat >> 3);
  const int n0 = (virt % 8) * 128;
  const int m0 = (virt / 8) * 256;

  f32x4 acc[4][4] = {};
  gemm_core_v5(A, W2T, m0, n0, sm, acc);

  const int isbf = *flag;
  unsigned short* out16 = (unsigned short*)outv;
  float* out32 = (float*)outv;
  const int t = threadIdx.x, lane = t & 63, w = t >> 6;
  const int wr = w >> 1, wc = w & 1;
  const int coln = lane & 15, rbase = (lane >> 4) * 4;
#pragma unroll
  for (int j = 0; j < 4; ++j) {
    int nn = n0 + 64*wc + 16*j + coln;
    float bias = bf2f(bproj[nn]);
#pragma unroll
    for (int i = 0; i < 4; ++i) {
#pragma unroll
      for (int rr = 0; rr < 4; ++rr) {
        int mm = m0 + 64*wr + 16*i + rbase + rr;
        float v = acc[i][j][rr] + bias;
        if (isbf) out16[(size_t)mm * ND + nn] = f2bf(v);
        else      out32[(size_t)mm * ND + nn] = v;
      }
    }
  }
}

// ---------- causal flash attention: R10 = zero-LDS-staging, zero-barrier waves ----------
// R5/R6/R8 pinned at ~85us across 3 sync structures: the shared trait was the
// barrier-lockstepped chain through LDS-staged K/V. Guide m169: when K/V L2-fits,
// LDS staging is pure overhead. Here K/V = 512KB/bh, ~8 bh/XCD = 4MB = L2-resident;
// co-resident blocks share bh (QTAB unchanged).
// All fragments load DIRECTLY global->VGPR (derived by composing the verified
// stage-write and swizzled-read formulas -- not guessed):
//   qa[i][f]  = qb [base + (q0+32w+16i+li)*64 + 32f + 8qd]   (16B aligned)
//   kfr[c][f] = kb [base + (k0+16c+li)*64   + 32f + 8qd]
//   vf[c2]    = vtb[base + (16c2+li)*2048   + k0  + 8qd]
// LDS = 16KB wave-private P scratch only (same swizzled layout; same-wave LDS
// ordering covers write->read and cross-tile WAR). NO barriers anywhere: 16
// desynced waves/CU hide L2/L1 latency by TLP; compiler pipelines the loads.
__global__ __launch_bounds__(256, 4) void attn_causal(const unsigned short* __restrict__ qb,
                                                      const unsigned short* __restrict__ kb,
                                                      const unsigned short* __restrict__ vtb,
                                                      unsigned short* __restrict__ ob) {
  __shared__ unsigned short Ps[128 * 64];            // 16KB: P scratch only

  int t = threadIdx.x, lane = t & 63, w = t >> 6;
  int qd = lane >> 4, li = lane & 15;
  int sw0 = ((qd ^ (li & 7)) * 8);

  const int qtab[4][4] = {{15,8,7,0},{14,9,6,1},{13,10,5,2},{12,11,4,3}};
  int bi = blockIdx.x;
  int bh = bi & 63;
  int qt = qtab[(bi >> 6) & 3][bi >> 8];
  int q0 = qt * 128;
  int NT = 4 * qt + 4;                       // number of 32-key tiles
  size_t base = (size_t)bh * NS * NE;
  int bb = bh >> 4, hh = bh & 15;

  const unsigned short* kbase = kb + base;
  const unsigned short* vbase = vtb + base;

  bf16x8 onesf;
#pragma unroll
  for (int j = 0; j < 8; ++j) onesf[j] = (__bf16)1.0f;

  // Q fragments direct from global (no LDS)
  bf16x8 qa[2][2];
#pragma unroll
  for (int i = 0; i < 2; ++i) {
    const unsigned short* qr = qb + base + (size_t)(q0 + 32*w + 16*i + li) * 64 + 8*qd;
    qa[i][0] = *(const bf16x8*)(qr);
    qa[i][1] = *(const bf16x8*)(qr + 32);
  }

  f32x4 o[2][4] = {};
  f32x4 lacc[2] = {};

  for (int kt = 0; kt < NT; ++kt) {
    int k0 = kt * 32;

    // K fragments direct from global
    bf16x8 kfr[2][2];
#pragma unroll
    for (int c = 0; c < 2; ++c) {
      const unsigned short* kr = kbase + (size_t)(k0 + 16*c + li) * 64 + 8*qd;
      kfr[c][0] = *(const bf16x8*)(kr);
      kfr[c][1] = *(const bf16x8*)(kr + 32);
    }

    int need_mask = (k0 >= q0);
#pragma unroll
    for (int i = 0; i < 2; ++i) {
#pragma unroll
      for (int c = 0; c < 2; ++c) {
        f32x4 s = {};
        s = __builtin_amdgcn_mfma_f32_16x16x32_bf16(qa[i][0], kfr[c][0], s, 0, 0, 0);
        s = __builtin_amdgcn_mfma_f32_16x16x32_bf16(qa[i][1], kfr[c][1], s, 0, 0, 0);
#pragma unroll
        for (int rr = 0; rr < 4; ++rr) {
          float pv = exp2f(s[rr]);
          if (need_mask) {
            int colk = k0 + 16*c + li;
            int rowq = q0 + 32*w + 16*i + qd*4 + rr;
            if (colk > rowq) pv = 0.f;
          }
          int prow = 32*w + 16*i + qd*4 + rr;
          int lo = 2*c + (li >> 3);
          Ps[prow * 64 + ((lo ^ (prow & 7)) * 8) + (li & 7)] =
              (unsigned short)(__float_as_uint(pv) >> 16);
        }
      }
    }

    // read P as A-operand (wave-local rows; same-wave LDS ordering => no barrier)
    bf16x8 pa[2];
#pragma unroll
    for (int i = 0; i < 2; ++i)
      pa[i] = *(const bf16x8*)(Ps + (32*w + 16*i + li) * 64 + sw0);

#pragma unroll
    for (int i = 0; i < 2; ++i)
      lacc[i] = __builtin_amdgcn_mfma_f32_16x16x32_bf16(pa[i], onesf, lacc[i], 0, 0, 0);

    // O += P V : V fragments direct from global (B,H,E,S layout)
#pragma unroll
    for (int c2 = 0; c2 < 4; ++c2) {
      bf16x8 vf = *(const bf16x8*)(vbase + (size_t)(16*c2 + li) * NS + k0 + 8*qd);
#pragma unroll
      for (int i = 0; i < 2; ++i)
        o[i][c2] = __builtin_amdgcn_mfma_f32_16x16x32_bf16(pa[i], vf, o[i][c2], 0, 0, 0);
    }
  }

  // write O to (B,S,H,E)
#pragma unroll
  for (int i = 0; i < 2; ++i)
#pragma unroll
    for (int c = 0; c < 4; ++c)
#pragma unroll
      for (int rr = 0; rr < 4; ++rr) {
        int rowm = 32*w + 16*i + qd*4 + rr;
        float inv = 1.0f / fmaxf(lacc[i][rr], 1e-30f);
        float ov = o[i][c][rr] * inv;
        int e = 16*c + li;
        ob[(((size_t)bb * NS + (q0 + rowm)) * NH + hh) * NE + e] = f2bf(ov);
      }
}

extern "C" void kernel_launch(void* const* d_in, const int* in_sizes, int n_in,
                              void* d_out, int out_size, void* d_ws, size_t ws_size,
                              hipStream_t stream) {
  (void)in_sizes; (void)n_in; (void)out_size; (void)ws_size;
  char* ws = (char*)d_ws;
  unsigned short* W1T = (unsigned short*)(ws);                       // 6,291,456
  unsigned short* W2T = (unsigned short*)(ws + 6291456);             // 2,097,152
  unsigned short* qb  = (unsigned short*)(ws + 8388608);             // 16 MB
  unsigned short* kb  = (unsigned short*)(ws + 25165824);            // 16 MB
  unsigned short* vb  = (unsigned short*)(ws + 41943040);            // 16 MB (B,H,E,S)
  unsigned short* ob  = (unsigned short*)(ws + 58720256);            // 16 MB
  unsigned short* bac = (unsigned short*)(ws + 75497472);            // 8 KB
  unsigned short* bpc = (unsigned short*)(ws + 75505664);            // 8 KB
  int*            flg = (int*)(ws + 75513856);
  unsigned short* xc  = ob;   // converted x, dead before ob written

  detect_dtype<<<1, 256, 0, stream>>>((const unsigned*)d_in[0], flg);
  conv_to_bf16<<<2048, 256, 0, stream>>>(d_in[0], xc,  NB*NS*ND, flg);
  conv_to_bf16<<<12,   256, 0, stream>>>(d_in[2], bac, 3*NH*NE, flg);
  conv_to_bf16<<<4,    256, 0, stream>>>(d_in[4], bpc, ND, flg);

  transpose_conv<<<dim3(3072/32, 1024/32), dim3(32, 8), 0, stream>>>(d_in[1], W1T, 1024, 3072, flg);
  transpose_conv<<<dim3(1024/32, 1024/32), dim3(32, 8), 0, stream>>>(d_in[3], W2T, 1024, 1024, flg);
  gemm_qkv_v5<<<dim3(3072/128, NM/256), 512, 0, stream>>>(xc, W1T, bac, qb, kb, vb);
  attn_causal<<<dim3(1024), 256, 0, stream>>>(qb, kb, vb, ob);
  gemm_proj_v5<<<dim3(1024/128, NM/256), 512, 0, stream>>>(ob, W2T, bpc, d_out, flg);
}

// Round 11
// 258.486 us; speedup vs baseline: 1.3735x; 1.2550x over previous
//
#include <hip/hip_runtime.h>

// Problem: B=4, S=2048, D=1024, H=16, HD=64.
#define NB 4
#define NS 2048
#define ND 1024
#define NH 16
#define NE 64
#define NM (NB*NS)   // 8192 rows

typedef __attribute__((ext_vector_type(8))) __bf16 bf16x8;           // MFMA A/B frag (4 VGPRs)
typedef __attribute__((ext_vector_type(4))) float f32x4;             // MFMA C/D frag

__device__ __forceinline__ float bf2f(unsigned short h) {
  union { unsigned u; float f; } c; c.u = ((unsigned)h) << 16; return c.f;
}
__device__ __forceinline__ unsigned short f2bf(float f) {
  union { float f; unsigned u; } c; c.f = f;
  return (unsigned short)((c.u + 0x7fffu + ((c.u >> 16) & 1u)) >> 16);
}
__device__ __forceinline__ void load16_to_lds(const void* g, void* l) {
  __builtin_amdgcn_global_load_lds(
      (__attribute__((address_space(1))) void*)(void*)(unsigned long long)(const char*)g,
      (__attribute__((address_space(3))) void*)l, 16, 0, 0);
}

// ---------- dtype detection: is d_in data bf16 (1) or fp32 (0)? ----------
__global__ void detect_dtype(const unsigned* __restrict__ x, int* __restrict__ flag) {
  __shared__ int cnt;
  if (threadIdx.x == 0) cnt = 0;
  __syncthreads();
  unsigned w = x[((unsigned)threadIdx.x * 16381u) & ((1u << 21) - 1u)];
  unsigned lo = w & 0xFFFFu;
  int e = (int)((lo >> 7) & 0xFF);
  int plausible = (lo == 0u) || (e >= 100 && e <= 142);
  atomicAdd(&cnt, plausible);
  __syncthreads();
  if (threadIdx.x == 0) *flag = (cnt >= 192) ? 1 : 0;
}

// ---------- merged, vectorized bf16 canonicalization (R11) ----------
// One launch converts x (8.4M), b_attn (3072), b_proj (1024). 4 elems/thread/iter:
// bf16 path = 8B copy; fp32 path = float4 read -> packed 8B store (G13: hipcc does
// not auto-vectorize bf16; scalar was ~2x slower).
__device__ __forceinline__ void conv4(const void* __restrict__ src,
                                      unsigned short* __restrict__ dst,
                                      int n4, int i0, int stride, int isbf) {
  if (isbf) {
    const unsigned long long* s = (const unsigned long long*)src;
    unsigned long long* d = (unsigned long long*)dst;
    for (int i = i0; i < n4; i += stride) d[i] = s[i];
  } else {
    const float4* s = (const float4*)src;
    unsigned long long* d = (unsigned long long*)dst;
    for (int i = i0; i < n4; i += stride) {
      float4 v = s[i];
      unsigned long long pk =  (unsigned long long)f2bf(v.x)
                            | ((unsigned long long)f2bf(v.y) << 16)
                            | ((unsigned long long)f2bf(v.z) << 32)
                            | ((unsigned long long)f2bf(v.w) << 48);
      d[i] = pk;
    }
  }
}

__global__ __launch_bounds__(256) void conv_all(const void* __restrict__ xs,
                                                unsigned short* __restrict__ xd,
                                                const void* __restrict__ bas,
                                                unsigned short* __restrict__ bad,
                                                const void* __restrict__ bps,
                                                unsigned short* __restrict__ bpd,
                                                const int* __restrict__ flag) {
  int isbf = *flag;
  int b = blockIdx.x;
  if (b < 2046) {
    conv4(xs, xd, (NB*NS*ND)/4, b * 256 + threadIdx.x, 2046 * 256, isbf);
  } else if (b == 2046) {
    conv4(bas, bad, (3*NH*NE)/4, threadIdx.x, 256, isbf);
  } else {
    conv4(bps, bpd, ND/4, threadIdx.x, 256, isbf);
  }
}

// ---------- fused convert+transpose: in[K][N] (bf16 or fp32 per flag) -> out[N][K] bf16 ----------
__global__ __launch_bounds__(256) void transpose_conv(const void* __restrict__ in,
                                                      unsigned short* __restrict__ out,
                                                      int K, int N, const int* __restrict__ flag) {
  __shared__ unsigned short tile[32][33];
  int n0 = blockIdx.x * 32, k0 = blockIdx.y * 32;
  int tx = threadIdx.x, ty = threadIdx.y;   // (32,8)
  if (*flag) {
    const unsigned short* p = (const unsigned short*)in;
#pragma unroll
    for (int i = 0; i < 4; ++i)
      tile[ty + 8*i][tx] = p[(size_t)(k0 + ty + 8*i) * N + n0 + tx];
  } else {
    const float* p = (const float*)in;
#pragma unroll
    for (int i = 0; i < 4; ++i)
      tile[ty + 8*i][tx] = f2bf(p[(size_t)(k0 + ty + 8*i) * N + n0 + tx]);
  }
  __syncthreads();
#pragma unroll
  for (int i = 0; i < 4; ++i)
    out[(size_t)(n0 + ty + 8*i) * K + k0 + tx] = tile[tx][ty + 8*i];
}

// ---------- v5 GEMM core: T3 minimum 2-phase recipe (guide-verified 622-682 TF class) ----
#define BUFB 49152            // bytes per buf: A 256*128 + B 128*128

__device__ __forceinline__ void gemm_core_v5(const unsigned short* __restrict__ Ag,
                                             const unsigned short* __restrict__ Btg,
                                             int m0, int n0,
                                             unsigned short* sm,
                                             f32x4 (&acc)[4][4]) {
  char* smb = (char*)sm;
  const int t = threadIdx.x;                 // 0..511
  const int lane = t & 63, w = t >> 6;       // 8 waves
  const int wr = w >> 1, wc = w & 1;         // 4M x 2N, wave tile 64x64
  const int frm = lane & 15, qd = lane >> 4;
  const int px0 = ((qd    ) ^ (frm & 7)) * 16;   // ks=0 swizzled chunk byte offset
  const int px1 = ((4 + qd) ^ (frm & 7)) * 16;   // ks=1
  const int NT = ND / 64;                    // 16 K-tiles

  auto stage = [&](int kt, int b) {
    char* Ab = smb + b * BUFB;
    char* Bb = Ab + 32768;
    int kk = kt * 64;
#pragma unroll
    for (int u = 0; u < 4; ++u) {            // A: 256x64 = 2048 chunks of 16B
      int ci = u * 512 + t;
      int row = ci >> 3, c = ci & 7, l = c ^ (row & 7);
      load16_to_lds(Ag + (size_t)(m0 + row) * ND + kk + l * 8, Ab + ci * 16);
    }
#pragma unroll
    for (int u = 0; u < 2; ++u) {            // B: 128x64 = 1024 chunks of 16B
      int ci = u * 512 + t;
      int row = ci >> 3, c = ci & 7, l = c ^ (row & 7);
      load16_to_lds(Btg + (size_t)(n0 + row) * ND + kk + l * 8, Bb + ci * 16);
    }
  };

  // prologue: stage tile 0 into buf 0, drain, barrier
  stage(0, 0);
  asm volatile("s_waitcnt vmcnt(0)\n\ts_barrier" ::: "memory");

  for (int kt = 0; kt < NT; ++kt) {
    const int cur = kt & 1;
    const char* Ab = smb + cur * BUFB;
    const char* Bb = Ab + 32768;

    if (kt + 1 < NT) stage(kt + 1, cur ^ 1);   // issue prefetch FIRST (stays in flight)

    bf16x8 a[4][2], b[4][2];
#pragma unroll
    for (int i = 0; i < 4; ++i) {
      int row = 64*wr + 16*i + frm;
      a[i][0] = *(const bf16x8*)(Ab + row * 128 + px0);
      a[i][1] = *(const bf16x8*)(Ab + row * 128 + px1);
    }
#pragma unroll
    for (int j = 0; j < 4; ++j) {
      int row = 64*wc + 16*j + frm;
      b[j][0] = *(const bf16x8*)(Bb + row * 128 + px0);
      b[j][1] = *(const bf16x8*)(Bb + row * 128 + px1);
    }
    asm volatile("s_waitcnt lgkmcnt(0)" ::: "memory");
    __builtin_amdgcn_s_setprio(1);
#pragma unroll
    for (int i = 0; i < 4; ++i)
#pragma unroll
      for (int j = 0; j < 4; ++j) {
        acc[i][j] = __builtin_amdgcn_mfma_f32_16x16x32_bf16(a[i][0], b[j][0], acc[i][j], 0, 0, 0);
        acc[i][j] = __builtin_amdgcn_mfma_f32_16x16x32_bf16(a[i][1], b[j][1], acc[i][j], 0, 0, 0);
      }
    __builtin_amdgcn_s_setprio(0);
    if (kt + 1 < NT)
      asm volatile("s_waitcnt vmcnt(0)\n\ts_barrier" ::: "memory");   // next tile ready
    // kt == NT-1: fall through to epilogue (register-only)
  }
}

// ---------- QKV projection, v5 core; scatter q/k:(B,H,S,E), v:(B,H,E,S) ----------
__global__ __launch_bounds__(512, 2) void gemm_qkv_v5(const unsigned short* __restrict__ X,
                                                      const unsigned short* __restrict__ W1T,
                                                      const unsigned short* __restrict__ battn,
                                                      unsigned short* __restrict__ qb,
                                                      unsigned short* __restrict__ kb,
                                                      unsigned short* __restrict__ vb) {
  __shared__ unsigned short sm[2 * 384 * 64];        // 96 KiB
  // XCD bijective swizzle: 768 = 8*96; XCD k owns 4 consecutive m-panels x all 24 n-panels.
  int flat = blockIdx.x + 24 * blockIdx.y;
  int virt = (flat & 7) * 96 + (flat >> 3);
  const int n0 = (virt % 24) * 128;
  const int m0 = (virt / 24) * 256;

  f32x4 acc[4][4] = {};
  gemm_core_v5(X, W1T, m0, n0, sm, acc);

  const int t = threadIdx.x, lane = t & 63, w = t >> 6;
  const int wr = w >> 1, wc = w & 1;
  const int coln = lane & 15, rbase = (lane >> 4) * 4;
#pragma unroll
  for (int j = 0; j < 4; ++j) {
    int nn = n0 + 64*wc + 16*j + coln;       // 0..3071
    int qq = nn >> 10;                       // 0=q 1=k 2=v
    int h  = (nn >> 6) & 15;
    int e  = nn & 63;
    float bias = bf2f(battn[nn]);
    float scale = (qq == 0) ? (0.125f * 1.44269504f) : 1.0f;
    if (qq == 2) {
      // V (B,H,E,S): 4 rr values are 4 consecutive s -> one 8B packed store
#pragma unroll
      for (int i = 0; i < 4; ++i) {
        int mm0 = m0 + 64*wr + 16*i + rbase;
        int bb = mm0 >> 11, s0 = mm0 & 2047;
        unsigned long long pk = 0;
#pragma unroll
        for (int rr = 0; rr < 4; ++rr) {
          float v = acc[i][j][rr] + bias;
          pk |= ((unsigned long long)f2bf(v)) << (16 * rr);
        }
        size_t idx = (((size_t)bb * NH + h) * NE + e) * NS + s0;
        *(unsigned long long*)(vb + idx) = pk;
      }
    } else {
      unsigned short* dst = (qq == 0) ? qb : kb;
#pragma unroll
      for (int i = 0; i < 4; ++i) {
#pragma unroll
        for (int rr = 0; rr < 4; ++rr) {
          int mm = m0 + 64*wr + 16*i + rbase + rr;
          int bb = mm >> 11, s = mm & 2047;
          float v = (acc[i][j][rr] + bias) * scale;
          dst[(((size_t)bb * NH + h) * NS + s) * NE + e] = f2bf(v);
        }
      }
    }
  }
}

// ---------- output projection, v5 core; store dtype per flag ----------
__global__ __launch_bounds__(512, 2) void gemm_proj_v5(const unsigned short* __restrict__ A,
                                                       const unsigned short* __restrict__ W2T,
                                                       const unsigned short* __restrict__ bproj,
                                                       void* __restrict__ outv,
                                                       const int* __restrict__ flag) {
  __shared__ unsigned short sm[2 * 384 * 64];        // 96 KiB
  // 256 blocks = exactly 1/CU; XCD swizzle: 256 = 8*32.
  int flat = blockIdx.x + 8 * blockIdx.y;
  int virt = (flat & 7) * 32 + (flat >> 3);
  const int n0 = (virt % 8) * 128;
  const int m0 = (virt / 8) * 256;

  f32x4 acc[4][4] = {};
  gemm_core_v5(A, W2T, m0, n0, sm, acc);

  const int isbf = *flag;
  unsigned short* out16 = (unsigned short*)outv;
  float* out32 = (float*)outv;
  const int t = threadIdx.x, lane = t & 63, w = t >> 6;
  const int wr = w >> 1, wc = w & 1;
  const int coln = lane & 15, rbase = (lane >> 4) * 4;
#pragma unroll
  for (int j = 0; j < 4; ++j) {
    int nn = n0 + 64*wc + 16*j + coln;
    float bias = bf2f(bproj[nn]);
#pragma unroll
    for (int i = 0; i < 4; ++i) {
#pragma unroll
      for (int rr = 0; rr < 4; ++rr) {
        int mm = m0 + 64*wr + 16*i + rbase + rr;
        float v = acc[i][j][rr] + bias;
        if (isbf) out16[(size_t)mm * ND + nn] = f2bf(v);
        else      out32[(size_t)mm * ND + nn] = v;
      }
    }
  }
}

// ---------- causal flash attention: R6-exact (best measured, 84.6-85.4 us) ----------
// 1024 fully-resident blocks, 4/CU; QTAB rows sum to 30 (per-CU balance + bh sharing).
// 128 q-rows/block, 32-key tiles, dbuf DMA, vmcnt(2). LDS 32KB.
// P-store offsets precomputed+pinned; row-sums accumulate in ones-MFMA C operand;
// stage_kv induction pointers.
__global__ __launch_bounds__(256, 4) void attn_causal(const unsigned short* __restrict__ qb,
                                                      const unsigned short* __restrict__ kb,
                                                      const unsigned short* __restrict__ vtb,
                                                      unsigned short* __restrict__ ob) {
  __shared__ unsigned short QPs[128 * 64];
  __shared__ unsigned short Ks[2][32 * 64];
  __shared__ unsigned short Vt[2][32 * 64];

  int t = threadIdx.x, lane = t & 63, w = t >> 6;
  int qd = lane >> 4, li = lane & 15;
  int sw0 = ((qd ^ (li & 7)) * 8);
  int sw1 = (((4 + qd) ^ (li & 7)) * 8);

  const int qtab[4][4] = {{15,8,7,0},{14,9,6,1},{13,10,5,2},{12,11,4,3}};
  int bi = blockIdx.x;
  int bh = bi & 63;
  int qt = qtab[(bi >> 6) & 3][bi >> 8];
  int q0 = qt * 128;
  int NT = 4 * qt + 4;                       // number of 32-key tiles
  size_t base = (size_t)bh * NS * NE;
  int bb = bh >> 4, hh = bh & 15;

  bf16x8 onesf;
#pragma unroll
  for (int j = 0; j < 8; ++j) onesf[j] = (__bf16)1.0f;

  // P-store byte offsets: loop-invariant; compute once, pin in VGPRs.
  unsigned pofs[2][2][4];
#pragma unroll
  for (int i = 0; i < 2; ++i)
#pragma unroll
    for (int c = 0; c < 2; ++c)
#pragma unroll
      for (int rr = 0; rr < 4; ++rr) {
        int prow = 32*w + 16*i + qd*4 + rr;
        int lo = 2*c + (li >> 3);
        pofs[i][c][rr] = (unsigned)((prow * 64 + ((lo ^ (prow & 7)) * 8) + (li & 7)) * 2);
        asm volatile("" : "+v"(pofs[i][c][rr]));
      }

  // stage_kv induction pointers (advance by one 32-key tile per call)
  int r8 = t >> 3, p8 = t & 7, lsw = p8 ^ (r8 & 7);
  const char* ksrc = (const char*)(kb + base + (size_t)r8 * NE + lsw * 8);
  int ve = 2 * r8 + (lsw >> 2);
  const char* vsrc = (const char*)(vtb + base + (size_t)ve * NS + (lsw & 3) * 8);
  char* kdst = (char*)Ks[0] + t * 16;        // buf stride 4096 B
  char* vdst = (char*)Vt[0] + t * 16;

  auto stage_kv = [&](int buf) {             // stages the NEXT sequential tile
    load16_to_lds(ksrc, kdst + buf * 4096);
    load16_to_lds(vsrc, vdst + buf * 4096);
    ksrc += 32 * NE * 2;                     // +4096 B: next 32 keys (rows)
    vsrc += 32 * 2;                          // +64 B: next 32 keys (cols of Vt)
  };

  // stage Q (128x64, swizzled) + first K/V tile
#pragma unroll
  for (int c = 0; c < 4; ++c) {
    int ch = c * 256 + t;
    int r = ch >> 3, jl = (ch & 7) ^ (r & 7);
    load16_to_lds(qb + base + (size_t)(q0 + r) * NE + jl * 8, (char*)QPs + ch * 16);
  }
  stage_kv(0);
  asm volatile("s_waitcnt vmcnt(2)\n\ts_barrier" ::: "memory");  // Q drained, kv0 in flight

  bf16x8 qa[2][2];
#pragma unroll
  for (int i = 0; i < 2; ++i) {
    const unsigned short* qr = QPs + (32*w + 16*i + li) * 64;
    qa[i][0] = *(const bf16x8*)(qr + sw0);
    qa[i][1] = *(const bf16x8*)(qr + sw1);
  }

  f32x4 o[2][4] = {};
  f32x4 lacc[2] = {};                        // row sums accumulated by MFMA C-in

  for (int kt = 0; kt < NT; ++kt) {
    int cur = kt & 1;
    // all waves done with buf[cur^1] (and, at kt=0, with their qa reads)
    asm volatile("s_waitcnt lgkmcnt(0)\n\ts_barrier" ::: "memory");
    if (kt + 1 < NT) {
      stage_kv(cur ^ 1);
      asm volatile("s_waitcnt vmcnt(2)\n\ts_barrier" ::: "memory");  // drain tile kt only
    } else {
      asm volatile("s_waitcnt vmcnt(0)\n\ts_barrier" ::: "memory");
    }

    int k0 = kt * 32;
    const unsigned short* Ksc = Ks[cur];
    const unsigned short* Vtc = Vt[cur];

    bf16x8 kfr[2][2];
#pragma unroll
    for (int c = 0; c < 2; ++c) {
      const unsigned short* kr = Ksc + (16*c + li) * 64;
      kfr[c][0] = *(const bf16x8*)(kr + sw0);
      kfr[c][1] = *(const bf16x8*)(kr + sw1);
    }

    int need_mask = (k0 >= q0);
#pragma unroll
    for (int i = 0; i < 2; ++i) {
#pragma unroll
      for (int c = 0; c < 2; ++c) {
        f32x4 s = {};
        s = __builtin_amdgcn_mfma_f32_16x16x32_bf16(qa[i][0], kfr[c][0], s, 0, 0, 0);
        s = __builtin_amdgcn_mfma_f32_16x16x32_bf16(qa[i][1], kfr[c][1], s, 0, 0, 0);
#pragma unroll
        for (int rr = 0; rr < 4; ++rr) {
          float pv = exp2f(s[rr]);
          if (need_mask) {
            int colk = k0 + 16*c + li;
            int rowq = q0 + 32*w + 16*i + qd*4 + rr;
            if (colk > rowq) pv = 0.f;
          }
          *(unsigned short*)((char*)QPs + pofs[i][c][rr]) =
              (unsigned short)(__float_as_uint(pv) >> 16);
        }
      }
    }

    // read P as A-operand (wave-local rows; in-order LDS => no barrier)
    bf16x8 pa[2];
#pragma unroll
    for (int i = 0; i < 2; ++i)
      pa[i] = *(const bf16x8*)(QPs + (32*w + 16*i + li) * 64 + sw0);

    // row sums via ones-MFMA, accumulated directly into lacc (C-in == C-out)
#pragma unroll
    for (int i = 0; i < 2; ++i)
      lacc[i] = __builtin_amdgcn_mfma_f32_16x16x32_bf16(pa[i], onesf, lacc[i], 0, 0, 0);

    // O += P V : B-frag from packed Vt (row = e>>1, octet = (e&1)*4+qd, swizzled)
#pragma unroll
    for (int c2 = 0; c2 < 4; ++c2) {
      const unsigned short* vr = Vtc + (8*c2 + (li >> 1)) * 64;
      bf16x8 vf = *(const bf16x8*)(vr + ((((li & 1) * 4 + qd) ^ ((li >> 1) & 7)) * 8));
#pragma unroll
      for (int i = 0; i < 2; ++i)
        o[i][c2] = __builtin_amdgcn_mfma_f32_16x16x32_bf16(pa[i], vf, o[i][c2], 0, 0, 0);
    }
  }

  // write O to (B,S,H,E)
#pragma unroll
  for (int i = 0; i < 2; ++i)
#pragma unroll
    for (int c = 0; c < 4; ++c)
#pragma unroll
      for (int rr = 0; rr < 4; ++rr) {
        int rowm = 32*w + 16*i + qd*4 + rr;
        float inv = 1.0f / fmaxf(lacc[i][rr], 1e-30f);
        float ov = o[i][c][rr] * inv;
        int e = 16*c + li;
        ob[(((size_t)bb * NS + (q0 + rowm)) * NH + hh) * NE + e] = f2bf(ov);
      }
}

extern "C" void kernel_launch(void* const* d_in, const int* in_sizes, int n_in,
                              void* d_out, int out_size, void* d_ws, size_t ws_size,
                              hipStream_t stream) {
  (void)in_sizes; (void)n_in; (void)out_size; (void)ws_size;
  char* ws = (char*)d_ws;
  unsigned short* W1T = (unsigned short*)(ws);                       // 6,291,456
  unsigned short* W2T = (unsigned short*)(ws + 6291456);             // 2,097,152
  unsigned short* qb  = (unsigned short*)(ws + 8388608);             // 16 MB
  unsigned short* kb  = (unsigned short*)(ws + 25165824);            // 16 MB
  unsigned short* vb  = (unsigned short*)(ws + 41943040);            // 16 MB (B,H,E,S)
  unsigned short* ob  = (unsigned short*)(ws + 58720256);            // 16 MB
  unsigned short* bac = (unsigned short*)(ws + 75497472);            // 8 KB
  unsigned short* bpc = (unsigned short*)(ws + 75505664);            // 8 KB
  int*            flg = (int*)(ws + 75513856);
  unsigned short* xc  = ob;   // converted x, dead before ob written

  detect_dtype<<<1, 256, 0, stream>>>((const unsigned*)d_in[0], flg);
  conv_all<<<2048, 256, 0, stream>>>(d_in[0], xc, d_in[2], bac, d_in[4], bpc, flg);

  transpose_conv<<<dim3(3072/32, 1024/32), dim3(32, 8), 0, stream>>>(d_in[1], W1T, 1024, 3072, flg);
  transpose_conv<<<dim3(1024/32, 1024/32), dim3(32, 8), 0, stream>>>(d_in[3], W2T, 1024, 1024, flg);
  gemm_qkv_v5<<<dim3(3072/128, NM/256), 512, 0, stream>>>(xc, W1T, bac, qb, kb, vb);
  attn_causal<<<dim3(1024), 256, 0, stream>>>(qb, kb, vb, ob);
  gemm_proj_v5<<<dim3(1024/128, NM/256), 512, 0, stream>>>(ob, W2T, bpc, d_out, flg);
}